// Round 1
// baseline (7888.316 us; speedup 1.0000x reference)
//
#include <hip/hip_runtime.h>
#include <math.h>

// ---------------------------------------------------------------------------
// AdaAttN block, f32 baseline.
// Layout convention: feature maps [C][N] row-major (N = H*W), batch = 1.
// ---------------------------------------------------------------------------

#define BM 64
#define BN 64
#define BK 16
#define BMP 68  // padded LDS row (16B-aligned rows, conflict-free staging)

__device__ inline float wave_max64(float v) {
#pragma unroll
    for (int o = 32; o > 0; o >>= 1) v = fmaxf(v, __shfl_xor(v, o, 64));
    return v;
}
__device__ inline float wave_sum64(float v) {
#pragma unroll
    for (int o = 32; o > 0; o >>= 1) v += __shfl_xor(v, o, 64);
    return v;
}

// C[M][N] (+bias per row m). If ATRANS: A is [K][lda] and C = A^T * B.
// Else: A is [M][lda] and C = A * B. B is always [K][ldb].
// M, N multiples of 64; K multiple of 16. Grid: (N/64, M/64), 256 threads.
template <bool ATRANS, bool BIAS>
__global__ __launch_bounds__(256) void gemm_kernel(
    const float* __restrict__ A, const float* __restrict__ B,
    const float* __restrict__ bias, float* __restrict__ C, int K, int lda,
    int ldb, int ldc) {
    __shared__ float As[BK][BMP];
    __shared__ float Bs[BK][BMP];
    const int t = threadIdx.x;
    const int tx = t & 15, ty = t >> 4;
    const int bm = blockIdx.y * BM, bn = blockIdx.x * BN;
    float acc[4][4] = {};
    for (int k0 = 0; k0 < K; k0 += BK) {
        if (ATRANS) {
            const int m = t & 63, ks = t >> 6;
#pragma unroll
            for (int kk = 0; kk < 4; kk++) {
                const int k = ks + kk * 4;
                As[k][m] = A[(size_t)(k0 + k) * lda + (bm + m)];
            }
        } else {
            const int k = t & 15, ms = t >> 4;
#pragma unroll
            for (int mm = 0; mm < 4; mm++) {
                const int m = ms + mm * 16;
                As[k][m] = A[(size_t)(bm + m) * lda + (k0 + k)];
            }
        }
        {
            const int n = t & 63, ks = t >> 6;
#pragma unroll
            for (int kk = 0; kk < 4; kk++) {
                const int k = ks + kk * 4;
                Bs[k][n] = B[(size_t)(k0 + k) * ldb + (bn + n)];
            }
        }
        __syncthreads();
#pragma unroll
        for (int kk = 0; kk < BK; kk++) {
            float a[4], b[4];
#pragma unroll
            for (int i = 0; i < 4; i++) a[i] = As[kk][ty * 4 + i];
#pragma unroll
            for (int j = 0; j < 4; j++) b[j] = Bs[kk][tx * 4 + j];
#pragma unroll
            for (int i = 0; i < 4; i++)
#pragma unroll
                for (int j = 0; j < 4; j++)
                    acc[i][j] = fmaf(a[i], b[j], acc[i][j]);
        }
        __syncthreads();
    }
#pragma unroll
    for (int i = 0; i < 4; i++) {
        const int m = bm + ty * 4 + i;
        const float bv = BIAS ? bias[m] : 0.0f;
#pragma unroll
        for (int j = 0; j < 4; j++)
            C[(size_t)m * ldc + (bn + tx * 4 + j)] = acc[i][j] + bv;
    }
}

// Dual-output NT GEMM: Cm[m][v] = sum_k S[m][k]*H[v][k],
//                      C2[m][v] = sum_k S[m][k]*H[v][k]^2.
// S: [M][K], H: [V][K], both row-major with ld == K. Grid: (V/64, M/64).
__global__ __launch_bounds__(256) void gemm_pv_kernel(
    const float* __restrict__ S, const float* __restrict__ H,
    float* __restrict__ Cm, float* __restrict__ C2, int K, int V) {
    __shared__ float As[BK][BMP];
    __shared__ float Bs[BK][BMP];
    const int t = threadIdx.x;
    const int tx = t & 15, ty = t >> 4;
    const int bm = blockIdx.y * BM, bn = blockIdx.x * BN;
    float acc1[4][4] = {};
    float acc2[4][4] = {};
    const int k = t & 15, ms = t >> 4;
    for (int k0 = 0; k0 < K; k0 += BK) {
#pragma unroll
        for (int mm = 0; mm < 4; mm++) {
            const int m = ms + mm * 16;
            As[k][m] = S[(size_t)(bm + m) * K + (k0 + k)];
            Bs[k][m] = H[(size_t)(bn + m) * K + (k0 + k)];
        }
        __syncthreads();
#pragma unroll
        for (int kk = 0; kk < BK; kk++) {
            float a[4], b[4], b2[4];
#pragma unroll
            for (int i = 0; i < 4; i++) a[i] = As[kk][ty * 4 + i];
#pragma unroll
            for (int j = 0; j < 4; j++) {
                b[j] = Bs[kk][tx * 4 + j];
                b2[j] = b[j] * b[j];
            }
#pragma unroll
            for (int i = 0; i < 4; i++)
#pragma unroll
                for (int j = 0; j < 4; j++) {
                    acc1[i][j] = fmaf(a[i], b[j], acc1[i][j]);
                    acc2[i][j] = fmaf(a[i], b2[j], acc2[i][j]);
                }
        }
        __syncthreads();
    }
#pragma unroll
    for (int i = 0; i < 4; i++) {
        const int m = bm + ty * 4 + i;
#pragma unroll
        for (int j = 0; j < 4; j++) {
            Cm[(size_t)m * V + (bn + tx * 4 + j)] = acc1[i][j];
            C2[(size_t)m * V + (bn + tx * 4 + j)] = acc2[i][j];
        }
    }
}

// Row softmax in place. One block per row.
__global__ __launch_bounds__(256) void softmax_kernel(float* __restrict__ S,
                                                      int cols) {
    __shared__ float red[8];
    const int t = threadIdx.x;
    float* p = S + (size_t)blockIdx.x * cols;
    float m = -1e30f;
    for (int c = t; c < cols; c += 256) m = fmaxf(m, p[c]);
    m = wave_max64(m);
    if ((t & 63) == 0) red[t >> 6] = m;
    __syncthreads();
    m = fmaxf(fmaxf(red[0], red[1]), fmaxf(red[2], red[3]));
    float s = 0.f;
    for (int c = t; c < cols; c += 256) {
        float e = __expf(p[c] - m);
        p[c] = e;
        s += e;
    }
    s = wave_sum64(s);
    if ((t & 63) == 0) red[4 + (t >> 6)] = s;
    __syncthreads();
    s = red[4] + red[5] + red[6] + red[7];
    const float inv = 1.0f / s;
    for (int c = t; c < cols; c += 256) p[c] *= inv;
}

// Per-channel mean and unbiased std (+1e-6) over N spatial. One block/channel.
__global__ __launch_bounds__(256) void chanstats_kernel(
    const float* __restrict__ x, float* __restrict__ cm,
    float* __restrict__ cstd, int N) {
    __shared__ float rs[4], rs2[4];
    const int t = threadIdx.x;
    const float* p = x + (size_t)blockIdx.x * N;
    float s = 0.f, s2 = 0.f;
    for (int i = t; i < N; i += 256) {
        float v = p[i];
        s += v;
        s2 = fmaf(v, v, s2);
    }
    s = wave_sum64(s);
    s2 = wave_sum64(s2);
    if ((t & 63) == 0) {
        rs[t >> 6] = s;
        rs2[t >> 6] = s2;
    }
    __syncthreads();
    if (t == 0) {
        float S = rs[0] + rs[1] + rs[2] + rs[3];
        float S2 = rs2[0] + rs2[1] + rs2[2] + rs2[3];
        float mean = S / N;
        float var = fmaxf((S2 - S * mean) / (N - 1), 0.f);
        cm[blockIdx.x] = mean;
        cstd[blockIdx.x] = sqrtf(var) + 1e-6f;
    }
}

// a5[c][n] = sqrt(relu(ex2-mean^2)) * (content-cm)/cstd + mean  (N = 4096)
__global__ __launch_bounds__(256) void epilogue5_kernel(
    const float* __restrict__ mean5, const float* __restrict__ ex25,
    const float* __restrict__ content, const float* __restrict__ cm,
    const float* __restrict__ cstd, float* __restrict__ a5) {
    int idx = blockIdx.x * 256 + threadIdx.x;  // c*4096 + n
    int c = idx >> 12, n = idx & 4095;
    float m = mean5[(size_t)n * 512 + c];
    float e2 = ex25[(size_t)n * 512 + c];
    float sd = sqrtf(fmaxf(e2 - m * m, 0.f));
    float cn = (content[idx] - cm[c]) / cstd[c];
    a5[idx] = fmaf(sd, cn, m);
    (void)n;
}

// sumbuf[c][n0+r] = a4 + upsample2(a5), for a 2048-row chunk of layer 4.
__global__ __launch_bounds__(256) void epilogue4_kernel(
    const float* __restrict__ meanc, const float* __restrict__ ex2c,
    const float* __restrict__ content, const float* __restrict__ cm,
    const float* __restrict__ cstd, const float* __restrict__ a5,
    float* __restrict__ sumbuf, int n0) {
    int idx = blockIdx.x * 256 + threadIdx.x;  // c*2048 + r
    int c = idx >> 11, r = idx & 2047;
    int n = n0 + r;
    float m = meanc[(size_t)r * 512 + c];
    float e2 = ex2c[(size_t)r * 512 + c];
    float sd = sqrtf(fmaxf(e2 - m * m, 0.f));
    float cn = (content[(size_t)c * 16384 + n] - cm[c]) / cstd[c];
    int y = n >> 7, x = n & 127;
    float up = a5[(size_t)c * 4096 + ((y >> 1) << 6) + (x >> 1)];
    sumbuf[(size_t)c * 16384 + n] = fmaf(sd, cn, m) + up;
}

// 3x3 conv, reflect pad 1, 128x128, 512->512 channels.
// Block: 256 threads = 16x16 spatial tile; 16 output channels per block.
__global__ __launch_bounds__(256) void conv3x3_kernel(
    const float* __restrict__ in, const float* __restrict__ w,
    const float* __restrict__ bias, float* __restrict__ out) {
    __shared__ float xs[18][18];
    __shared__ float wsm[16][9];
    const int t = threadIdx.x;
    const int tx = t & 15, ty = t >> 4;
    const int x0 = (blockIdx.x & 7) << 4;
    const int y0 = ((blockIdx.x >> 3) & 7) << 4;
    const int o0 = (blockIdx.x >> 6) << 4;
    float acc[16];
#pragma unroll
    for (int o = 0; o < 16; o++) acc[o] = bias[o0 + o];
    for (int i = 0; i < 512; i++) {
        __syncthreads();
        for (int idx = t; idx < 324; idx += 256) {
            int ly = idx / 18, lx = idx - ly * 18;
            int gy = y0 + ly - 1, gx = x0 + lx - 1;
            gy = gy < 0 ? 1 : (gy > 127 ? 126 : gy);
            gx = gx < 0 ? 1 : (gx > 127 ? 126 : gx);
            xs[ly][lx] = in[(size_t)i * 16384 + gy * 128 + gx];
        }
        if (t < 144) {
            int o = t / 9, r = t - o * 9;
            wsm[o][r] = w[(size_t)((o0 + o) * 512 + i) * 9 + r];
        }
        __syncthreads();
        float xv[9];
#pragma unroll
        for (int dy = 0; dy < 3; dy++)
#pragma unroll
            for (int dx = 0; dx < 3; dx++) xv[dy * 3 + dx] = xs[ty + dy][tx + dx];
#pragma unroll
        for (int o = 0; o < 16; o++) {
            float s = acc[o];
#pragma unroll
            for (int r = 0; r < 9; r++) s = fmaf(wsm[o][r], xv[r], s);
            acc[o] = s;
        }
    }
    const int outbase = (y0 + ty) * 128 + x0 + tx;
#pragma unroll
    for (int o = 0; o < 16; o++) out[(size_t)(o0 + o) * 16384 + outbase] = acc[o];
}

// ---------------------------------------------------------------------------

static inline void gemm_nn(const float* A, const float* B, const float* bias,
                           float* C, int M, int N, int K, int lda, int ldb,
                           int ldc, hipStream_t s) {
    dim3 g(N / 64, M / 64);
    gemm_kernel<false, true><<<g, 256, 0, s>>>(A, B, bias, C, K, lda, ldb, ldc);
}
static inline void gemm_tn(const float* A, const float* B, float* C, int M,
                           int N, int K, int lda, int ldb, int ldc,
                           hipStream_t s) {
    dim3 g(N / 64, M / 64);
    gemm_kernel<true, false><<<g, 256, 0, s>>>(A, B, nullptr, C, K, lda, ldb,
                                               ldc);
}

extern "C" void kernel_launch(void* const* d_in, const int* in_sizes, int n_in,
                              void* d_out, int out_size, void* d_ws,
                              size_t ws_size, hipStream_t stream) {
    (void)in_sizes; (void)n_in; (void)out_size; (void)ws_size;
    const float* content4 = (const float*)d_in[0];
    const float* style4 = (const float*)d_in[1];
    const float* content5 = (const float*)d_in[2];
    const float* style5 = (const float*)d_in[3];
    const float* ckey4 = (const float*)d_in[4];
    const float* skey4 = (const float*)d_in[5];
    const float* ckey5 = (const float*)d_in[6];
    const float* skey5 = (const float*)d_in[7];
    const float* f4w = (const float*)d_in[8];
    const float* f4b = (const float*)d_in[9];
    const float* g4w = (const float*)d_in[10];
    const float* g4b = (const float*)d_in[11];
    const float* h4w = (const float*)d_in[12];
    const float* h4b = (const float*)d_in[13];
    const float* f5w = (const float*)d_in[14];
    const float* f5b = (const float*)d_in[15];
    const float* g5w = (const float*)d_in[16];
    const float* g5b = (const float*)d_in[17];
    const float* h5w = (const float*)d_in[18];
    const float* h5b = (const float*)d_in[19];
    const float* convw = (const float*)d_in[20];
    const float* convb = (const float*)d_in[21];
    float* out = (float*)d_out;

    float* ws = (float*)d_ws;
    float* sumbuf = ws;                // 512*16384
    float* a5 = ws + 8388608;          // 512*4096
    float* cm4 = ws + 10485760;        // 512
    float* cstd4 = cm4 + 512;
    float* cm5 = cm4 + 1024;
    float* cstd5 = cm4 + 1536;
    float* arena = ws + 10487808;

    // ---- Layer 5: Nc=4096, Ns=1024, Ck=1472, Cv=512 ----
    {
        float* F5 = arena;               // 1472*4096
        float* G5 = F5 + 6029312;        // 1472*1024
        float* H5 = G5 + 1507328;        // 512*1024
        float* S5 = H5 + 524288;         // 4096*1024
        float* mean5 = S5 + 4194304;     // 4096*512
        float* ex25 = mean5 + 2097152;   // 4096*512

        gemm_nn(f5w, ckey5, f5b, F5, 1472, 4096, 1472, 1472, 4096, 4096, stream);
        gemm_nn(g5w, skey5, g5b, G5, 1472, 1024, 1472, 1472, 1024, 1024, stream);
        gemm_nn(h5w, style5, h5b, H5, 512, 1024, 512, 512, 1024, 1024, stream);
        gemm_tn(F5, G5, S5, 4096, 1024, 1472, 4096, 1024, 1024, stream);
        softmax_kernel<<<4096, 256, 0, stream>>>(S5, 1024);
        {
            dim3 g(512 / 64, 4096 / 64);
            gemm_pv_kernel<<<g, 256, 0, stream>>>(S5, H5, mean5, ex25, 1024, 512);
        }
        chanstats_kernel<<<512, 256, 0, stream>>>(content5, cm5, cstd5, 4096);
        epilogue5_kernel<<<8192, 256, 0, stream>>>(mean5, ex25, content5, cm5,
                                                   cstd5, a5);
    }

    // ---- Layer 4: Nc=16384, Ns=4096, Ck=960, Cv=512, chunked rows ----
    {
        float* G4 = arena;              // 960*4096
        float* H4 = G4 + 3932160;       // 512*4096
        float* Fc = H4 + 2097152;       // 960*2048
        float* Sc = Fc + 1966080;       // 2048*4096
        float* meanc = Sc + 8388608;    // 2048*512
        float* ex2c = meanc + 1048576;  // 2048*512

        chanstats_kernel<<<512, 256, 0, stream>>>(content4, cm4, cstd4, 16384);
        gemm_nn(g4w, skey4, g4b, G4, 960, 4096, 960, 960, 4096, 4096, stream);
        gemm_nn(h4w, style4, h4b, H4, 512, 4096, 512, 512, 4096, 4096, stream);

        for (int chunk = 0; chunk < 8; chunk++) {
            const int n0 = chunk * 2048;
            // F columns n0..n0+2047:  Fc[960][2048]
            gemm_nn(f4w, ckey4 + n0, f4b, Fc, 960, 2048, 960, 960, 16384, 2048,
                    stream);
            gemm_tn(Fc, G4, Sc, 2048, 4096, 960, 2048, 4096, 4096, stream);
            softmax_kernel<<<2048, 256, 0, stream>>>(Sc, 4096);
            {
                dim3 g(512 / 64, 2048 / 64);
                gemm_pv_kernel<<<g, 256, 0, stream>>>(Sc, H4, meanc, ex2c, 4096,
                                                      512);
            }
            epilogue4_kernel<<<4096, 256, 0, stream>>>(
                meanc, ex2c, content4, cm4, cstd4, a5, sumbuf, n0);
        }
    }

    // ---- Final 3x3 reflect conv ----
    conv3x3_kernel<<<2048, 256, 0, stream>>>(sumbuf, convw, convb, out);
}

// Round 3
// 3591.973 us; speedup vs baseline: 2.1961x; 2.1961x over previous
//
#include <hip/hip_runtime.h>
#include <math.h>

// ---------------------------------------------------------------------------
// AdaAttN on MI355X. Attention logits via split-fp16 (hi+lo, 3-MFMA) GEMMs
// with folded weights M = Wf^T Wg (softmax row-invariance kills one bias
// term; the other is a rank-1 r[m] correction). Value/conv GEMMs in fp16
// MFMA. f32 for logits, softmax, stats, epilogues.
// ---------------------------------------------------------------------------

typedef _Float16 half8 __attribute__((ext_vector_type(8)));
typedef float f32x4 __attribute__((ext_vector_type(4)));

__device__ __forceinline__ void async16(const void* g, void* lds) {
    __builtin_amdgcn_global_load_lds(
        (const __attribute__((address_space(1))) void*)g,
        (__attribute__((address_space(3))) void*)lds, 16, 0, 0);
}

__device__ inline float wave_sum64(float v) {
#pragma unroll
    for (int o = 32; o > 0; o >>= 1) v += __shfl_xor(v, o, 64);
    return v;
}

// ---------------------------------------------------------------------------
// Split-precision GEMM: C[m][n] = sum_k A[m][k]*B[n][k], A/B f32 k-contig,
// C f32. Each fp16 fragment split into hi+lo; 3 MFMAs per tile-pair.
// M,N multiples of 128; K multiple of 32. LDS chunk-XOR swizzle (row&7).
// ---------------------------------------------------------------------------
__global__ __launch_bounds__(256, 2) void mgemm_split(
    const float* __restrict__ A, const float* __restrict__ B,
    float* __restrict__ C, int K, int lda, int ldb, int ldc) {
    __shared__ float As[128 * 32];
    __shared__ float Bs[128 * 32];
    const int t = threadIdx.x, wave = t >> 6, lane = t & 63;
    const int bm = blockIdx.y * 128, bn = blockIdx.x * 128;
    const int wr = (wave >> 1) * 64, wc = (wave & 1) * 64;
    const int lq = lane >> 4, lr = lane & 15;
    const int r8 = lane >> 3;        // 0..7 row within 8-row issue
    const int cg = (lane & 7) ^ r8;  // swizzled global 16B-chunk index

    f32x4 acc[4][4] = {};

    const char* Ap =
        (const char*)(A + (size_t)(bm + wave * 32 + r8) * lda) + cg * 16;
    const char* Bp =
        (const char*)(B + (size_t)(bn + wave * 32 + r8) * ldb) + cg * 16;
    const size_t arow8 = (size_t)8 * lda * 4, brow8 = (size_t)8 * ldb * 4;
    float* AsW = &As[wave * 32 * 32];
    float* BsW = &Bs[wave * 32 * 32];
    const int key = lr & 7;

    for (int k0 = 0; k0 < K; k0 += 32) {
        __syncthreads();
#pragma unroll
        for (int q = 0; q < 4; q++) {
            async16(Ap + q * arow8, AsW + q * 256);
            async16(Bp + q * brow8, BsW + q * 256);
        }
        Ap += 128;
        Bp += 128;
        __syncthreads();

        half8 ah[4], al[4], bh[4], bl[4];
#pragma unroll
        for (int i = 0; i < 4; i++) {
            const float* p = &As[(wr + i * 16 + lr) * 32];
            f32x4 u0 = *(const f32x4*)(p + (((lq * 2) ^ key) * 4));
            f32x4 u1 = *(const f32x4*)(p + (((lq * 2 + 1) ^ key) * 4));
            half8 hi, lo;
#pragma unroll
            for (int e = 0; e < 4; e++) {
                _Float16 h0 = (_Float16)u0[e];
                hi[e] = h0;
                lo[e] = (_Float16)(u0[e] - (float)h0);
                _Float16 h1 = (_Float16)u1[e];
                hi[4 + e] = h1;
                lo[4 + e] = (_Float16)(u1[e] - (float)h1);
            }
            ah[i] = hi;
            al[i] = lo;
        }
#pragma unroll
        for (int j = 0; j < 4; j++) {
            const float* p = &Bs[(wc + j * 16 + lr) * 32];
            f32x4 u0 = *(const f32x4*)(p + (((lq * 2) ^ key) * 4));
            f32x4 u1 = *(const f32x4*)(p + (((lq * 2 + 1) ^ key) * 4));
            half8 hi, lo;
#pragma unroll
            for (int e = 0; e < 4; e++) {
                _Float16 h0 = (_Float16)u0[e];
                hi[e] = h0;
                lo[e] = (_Float16)(u0[e] - (float)h0);
                _Float16 h1 = (_Float16)u1[e];
                hi[4 + e] = h1;
                lo[4 + e] = (_Float16)(u1[e] - (float)h1);
            }
            bh[j] = hi;
            bl[j] = lo;
        }
#pragma unroll
        for (int i = 0; i < 4; i++)
#pragma unroll
            for (int j = 0; j < 4; j++) {
                acc[i][j] = __builtin_amdgcn_mfma_f32_16x16x32_f16(
                    ah[i], bl[j], acc[i][j], 0, 0, 0);
                acc[i][j] = __builtin_amdgcn_mfma_f32_16x16x32_f16(
                    al[i], bh[j], acc[i][j], 0, 0, 0);
                acc[i][j] = __builtin_amdgcn_mfma_f32_16x16x32_f16(
                    ah[i], bh[j], acc[i][j], 0, 0, 0);
            }
    }
#pragma unroll
    for (int i = 0; i < 4; i++) {
        const int m0 = bm + wr + i * 16 + lq * 4;
#pragma unroll
        for (int j = 0; j < 4; j++) {
            const int n = bn + wc + j * 16 + lr;
#pragma unroll
            for (int r = 0; r < 4; r++)
                C[(size_t)(m0 + r) * ldc + n] = acc[i][j][r];
        }
    }
}

// ---------------------------------------------------------------------------
// fp16 GEMM: C[m][n] = sum_k A[m][k]*B[n][k] (+bias). A,B fp16 k-contig.
// BIAS_MODE: 0 none, 2 bias[m]. OUT_MODE: 0 f32->Cf(+z*splitStride),
// 2 fp16 dual rows (v at m, v*v at m+512). CONV: B = pad4T[py][px][ci].
// ---------------------------------------------------------------------------
template <int BIAS_MODE, int OUT_MODE, bool CONV>
__global__ __launch_bounds__(256, 2) void mgemm16(
    const _Float16* __restrict__ A, const _Float16* __restrict__ B,
    const float* __restrict__ bias, float* __restrict__ Cf,
    _Float16* __restrict__ Ch, int K, int lda, int ldb, int ldc,
    size_t splitStride) {
    __shared__ _Float16 As[128 * 32];
    __shared__ _Float16 Bs[128 * 32];
    const int t = threadIdx.x, wave = t >> 6, lane = t & 63;
    const int bm = blockIdx.y * 128, bn = blockIdx.x * 128;
    const int kbase = blockIdx.z * K;
    const int wr = (wave >> 1) * 64, wc = (wave & 1) * 64;
    const int lq = lane >> 4, lr = lane & 15;
    const int srow = wave * 32 + (lane >> 2);
    const int scolg = (lane & 3) ^ ((lane >> 3) & 3);  // swizzled chunk

    f32x4 acc[4][4] = {};

    const char* Ap = (const char*)A +
                     ((size_t)(bm + srow) * lda + kbase) * 2 + scolg * 16;
    const char* Bp = (const char*)B +
                     ((size_t)(bn + srow) * ldb + kbase) * 2 + scolg * 16;
    const size_t Astep = (size_t)16 * lda * 2;
    const size_t Bstep = (size_t)16 * ldb * 2;
    _Float16* As0 = &As[(wave * 32) * 32];
    _Float16* As1 = &As[(wave * 32 + 16) * 32];
    _Float16* Bs0 = &Bs[(wave * 32) * 32];
    _Float16* Bs1 = &Bs[(wave * 32 + 16) * 32];
    const int key = (lr >> 1) & 3;

    for (int k0 = 0; k0 < K; k0 += 32) {
        __syncthreads();
        async16(Ap, As0);
        async16(Ap + Astep, As1);
        if (CONV) {
            const int kg = kbase + k0;
            const int rI = kg >> 9;
            const int dy = rI / 3, dx = rI - 3 * dy;
            const int ci0 = kg & 511;
            const char* Bc =
                (const char*)B +
                (((size_t)(blockIdx.x + dy) * 130 + srow + dx) * 512 + ci0) * 2 +
                scolg * 16;
            async16(Bc, Bs0);
            async16(Bc + (size_t)16 * 512 * 2, Bs1);
        } else {
            async16(Bp, Bs0);
            async16(Bp + Bstep, Bs1);
            Bp += 64;
        }
        Ap += 64;
        __syncthreads();

        half8 af[4], bf[4];
#pragma unroll
        for (int i = 0; i < 4; i++)
            af[i] = *(const half8*)&As[(wr + i * 16 + lr) * 32 + (lq ^ key) * 8];
#pragma unroll
        for (int j = 0; j < 4; j++)
            bf[j] = *(const half8*)&Bs[(wc + j * 16 + lr) * 32 + (lq ^ key) * 8];
#pragma unroll
        for (int i = 0; i < 4; i++)
#pragma unroll
            for (int j = 0; j < 4; j++)
                acc[i][j] = __builtin_amdgcn_mfma_f32_16x16x32_f16(
                    af[i], bf[j], acc[i][j], 0, 0, 0);
    }

    float* Co = (OUT_MODE == 0) ? Cf + (size_t)blockIdx.z * splitStride : nullptr;
#pragma unroll
    for (int i = 0; i < 4; i++) {
        const int m0 = bm + wr + i * 16 + lq * 4;
#pragma unroll
        for (int j = 0; j < 4; j++) {
            const int n = bn + wc + j * 16 + lr;
#pragma unroll
            for (int r = 0; r < 4; r++) {
                const int m = m0 + r;
                float v = acc[i][j][r];
                if (BIAS_MODE == 2) v += bias[m];
                if (OUT_MODE == 0) {
                    Co[(size_t)m * ldc + n] = v;
                } else {
                    Ch[(size_t)m * ldc + n] = (_Float16)v;
                    Ch[(size_t)(m + 512) * ldc + n] = (_Float16)(v * v);
                }
            }
        }
    }
}

// ---------------------------------------------------------------------------
// transpose f32->f32: src [C][srcld], dst [Nr][dstld]; dst row n = src col n,
// zero for n >= nvalid. grid (Nr/32, C/32).
__global__ __launch_bounds__(256) void transpose_f32(
    const float* __restrict__ src, float* __restrict__ dst, long srcld,
    int dstld, int nvalid) {
    __shared__ float tile[32][33];
    const int t = threadIdx.x, tx = t & 31, ty = t >> 5;
    const int n0 = blockIdx.x * 32, c0 = blockIdx.y * 32;
    const int n = n0 + tx;
#pragma unroll
    for (int i = 0; i < 4; i++) {
        int c = c0 + ty + i * 8;
        tile[ty + i * 8][tx] = (n < nvalid) ? src[(size_t)c * srcld + n] : 0.f;
    }
    __syncthreads();
#pragma unroll
    for (int i = 0; i < 4; i++) {
        int nn = ty + i * 8;
        dst[(size_t)(n0 + nn) * dstld + c0 + tx] = tile[tx][nn];
    }
}

// transpose f32->fp16 (full-valid). src [C][srcld], dst fp16 [N][dstld].
__global__ __launch_bounds__(256) void transpose_cvt16(
    const float* __restrict__ src, _Float16* __restrict__ dst, long srcld,
    int dstld) {
    __shared__ float tile[32][33];
    const int t = threadIdx.x, tx = t & 31, ty = t >> 5;
    const int n0 = blockIdx.x * 32, c0 = blockIdx.y * 32;
#pragma unroll
    for (int i = 0; i < 4; i++)
        tile[ty + i * 8][tx] = src[(size_t)(c0 + ty + i * 8) * srcld + n0 + tx];
    __syncthreads();
#pragma unroll
    for (int i = 0; i < 4; i++) {
        int nn = ty + i * 8;
        dst[(size_t)(n0 + nn) * dstld + c0 + tx] = (_Float16)tile[tx][nn];
    }
}

// elementwise f32 -> fp16
__global__ __launch_bounds__(256) void cvt16(const float* __restrict__ src,
                                             _Float16* __restrict__ dst) {
    int i = blockIdx.x * 256 + threadIdx.x;
    dst[i] = (_Float16)src[i];
}

// conv weight permute: [o][ci][3][3] f32 -> [o][(dy*3+dx)*512+ci] fp16
__global__ __launch_bounds__(256) void convw_perm(const float* __restrict__ src,
                                                  _Float16* __restrict__ dst) {
    int idx = blockIdx.x * 256 + threadIdx.x;
    int o = idx / 4608, rem = idx - o * 4608;
    int r = rem >> 9, ci = rem & 511;
    dst[idx] = (_Float16)src[(size_t)o * 4608 + ci * 9 + r];
}

// u[l] = sum_c bf[c] * Wg[c][l]
__global__ __launch_bounds__(256) void fold_u(const float* __restrict__ bf,
                                              const float* __restrict__ Wg,
                                              float* __restrict__ u, int C,
                                              int L) {
    int l = blockIdx.x * 256 + threadIdx.x;
    if (l >= L) return;
    float s = 0.f;
    for (int c = 0; c < C; c++) s = fmaf(bf[c], Wg[(size_t)c * L + l], s);
    u[l] = s;
}

// r[m] = sum_l u[l]*sk[l][m] + dot(bf,bg)
__global__ __launch_bounds__(256) void fold_r(const float* __restrict__ u,
                                              const float* __restrict__ sk,
                                              const float* __restrict__ bf,
                                              const float* __restrict__ bg,
                                              float* __restrict__ r, int L,
                                              int M, int C) {
    int m = blockIdx.x * 256 + threadIdx.x;
    if (m >= M) return;
    float s = 0.f;
    for (int c = 0; c < C; c++) s = fmaf(bf[c], bg[c], s);
    for (int l = 0; l < L; l++) s = fmaf(u[l], sk[(size_t)l * M + m], s);
    r[m] = s;
}

// Softmax: f32 logits row (+r[col]) -> fp16 probs row. One block per row.
__global__ __launch_bounds__(256) void softmax_f16(
    const float* __restrict__ L, const float* __restrict__ rr,
    _Float16* __restrict__ S, int cols) {
    __shared__ float red_m[4], red_s[4];
    const int t = threadIdx.x;
    const float* p = L + (size_t)blockIdx.x * cols;
    _Float16* q = S + (size_t)blockIdx.x * cols;
    float mt = -3.0e38f, st = 0.f;
    for (int c = t; c < cols; c += 256) {
        float v = p[c] + rr[c];
        if (v > mt) {
            st = st * __expf(mt - v) + 1.f;
            mt = v;
        } else {
            st += __expf(v - mt);
        }
    }
#pragma unroll
    for (int o = 32; o > 0; o >>= 1) {
        float m2 = __shfl_xor(mt, o, 64), s2 = __shfl_xor(st, o, 64);
        float m = fmaxf(mt, m2);
        st = st * __expf(mt - m) + s2 * __expf(m2 - m);
        mt = m;
    }
    if ((t & 63) == 0) {
        red_m[t >> 6] = mt;
        red_s[t >> 6] = st;
    }
    __syncthreads();
    float M = fmaxf(fmaxf(red_m[0], red_m[1]), fmaxf(red_m[2], red_m[3]));
    float Ssum = red_s[0] * __expf(red_m[0] - M) +
                 red_s[1] * __expf(red_m[1] - M) +
                 red_s[2] * __expf(red_m[2] - M) +
                 red_s[3] * __expf(red_m[3] - M);
    float inv = 1.f / Ssum;
    for (int c = t; c < cols; c += 256)
        q[c] = (_Float16)(__expf(p[c] + rr[c] - M) * inv);
}

// Per-channel mean & unbiased std (+1e-6). One block per channel.
__global__ __launch_bounds__(256) void chanstats_kernel(
    const float* __restrict__ x, float* __restrict__ cm,
    float* __restrict__ cstd, int N) {
    __shared__ float rs[4], rs2[4];
    const int t = threadIdx.x;
    const float* p = x + (size_t)blockIdx.x * N;
    float s = 0.f, s2 = 0.f;
    for (int i = t; i < N; i += 256) {
        float v = p[i];
        s += v;
        s2 = fmaf(v, v, s2);
    }
    s = wave_sum64(s);
    s2 = wave_sum64(s2);
    if ((t & 63) == 0) {
        rs[t >> 6] = s;
        rs2[t >> 6] = s2;
    }
    __syncthreads();
    if (t == 0) {
        float S = rs[0] + rs[1] + rs[2] + rs[3];
        float S2 = rs2[0] + rs2[1] + rs2[2] + rs2[3];
        float mean = S / N;
        float var = fmaxf((S2 - S * mean) / (N - 1), 0.f);
        cm[blockIdx.x] = mean;
        cstd[blockIdx.x] = sqrtf(var) + 1e-6f;
    }
}

// a5T[n][c] fp16 = std*instnorm(content5) + mean
__global__ __launch_bounds__(256) void epilogue5(
    const float* __restrict__ pv, const float* __restrict__ content,
    const float* __restrict__ cm, const float* __restrict__ cstd,
    _Float16* __restrict__ a5t) {
    int idx = blockIdx.x * 256 + threadIdx.x;  // n*512 + c
    int n = idx >> 9, c = idx & 511;
    float mean = pv[(size_t)n * 1024 + c];
    float ex2 = pv[(size_t)n * 1024 + 512 + c];
    float sd = sqrtf(fmaxf(ex2 - mean * mean, 0.f));
    float cn = (content[(size_t)c * 4096 + n] - cm[c]) / cstd[c];
    a5t[idx] = (_Float16)(fmaf(sd, cn, mean));
}

// pad4T interior <- a4 + upsample2(a5), one 1024-pixel chunk, 4 K-splits.
__global__ __launch_bounds__(256) void epilogue4(
    const float* __restrict__ part, const float* __restrict__ content,
    const float* __restrict__ cm, const float* __restrict__ cstd,
    const _Float16* __restrict__ a5t, _Float16* __restrict__ pad4t, int n0) {
    int idx = blockIdx.x * 256 + threadIdx.x;  // r*512 + c
    int r = idx >> 9, c = idx & 511;
    int n = n0 + r;
    const size_t SS = (size_t)1024 * 1024;
    float mean = 0.f, ex2 = 0.f;
#pragma unroll
    for (int z = 0; z < 4; z++) {
        mean += part[z * SS + (size_t)r * 1024 + c];
        ex2 += part[z * SS + (size_t)r * 1024 + 512 + c];
    }
    float sd = sqrtf(fmaxf(ex2 - mean * mean, 0.f));
    float cn = (content[(size_t)c * 16384 + n] - cm[c]) / cstd[c];
    int y = n >> 7, x = n & 127;
    float up = (float)a5t[(size_t)((y >> 1) * 64 + (x >> 1)) * 512 + c];
    pad4t[(size_t)((y + 1) * 130 + (x + 1)) * 512 + c] =
        (_Float16)(fmaf(sd, cn, mean) + up);
}

__global__ __launch_bounds__(256) void border_kernel(_Float16* __restrict__ pad) {
    int idx = blockIdx.x * 256 + threadIdx.x;  // pos*512 + c
    int pos = idx >> 9, c = idx & 511;
    int py, px;
    if (pos < 130) { py = 0; px = pos; }
    else if (pos < 260) { py = 129; px = pos - 130; }
    else if (pos < 388) { py = pos - 260 + 1; px = 0; }
    else { py = pos - 388 + 1; px = 129; }
    int sy = py == 0 ? 2 : (py == 129 ? 127 : py);
    int sx = px == 0 ? 2 : (px == 129 ? 127 : px);
    pad[(size_t)(py * 130 + px) * 512 + c] =
        pad[(size_t)(sy * 130 + sx) * 512 + c];
}

// ---------------------------------------------------------------------------

extern "C" void kernel_launch(void* const* d_in, const int* in_sizes, int n_in,
                              void* d_out, int out_size, void* d_ws,
                              size_t ws_size, hipStream_t stream) {
    (void)in_sizes; (void)n_in; (void)out_size; (void)ws_size;
    const float* content4 = (const float*)d_in[0];
    const float* style4 = (const float*)d_in[1];
    const float* content5 = (const float*)d_in[2];
    const float* style5 = (const float*)d_in[3];
    const float* ckey4 = (const float*)d_in[4];
    const float* skey4 = (const float*)d_in[5];
    const float* ckey5 = (const float*)d_in[6];
    const float* skey5 = (const float*)d_in[7];
    const float* f4w = (const float*)d_in[8];
    const float* f4b = (const float*)d_in[9];
    const float* g4w = (const float*)d_in[10];
    const float* g4b = (const float*)d_in[11];
    const float* h4w = (const float*)d_in[12];
    const float* h4b = (const float*)d_in[13];
    const float* f5w = (const float*)d_in[14];
    const float* f5b = (const float*)d_in[15];
    const float* g5w = (const float*)d_in[16];
    const float* g5b = (const float*)d_in[17];
    const float* h5w = (const float*)d_in[18];
    const float* h5b = (const float*)d_in[19];
    const float* convw = (const float*)d_in[20];
    const float* convb = (const float*)d_in[21];
    float* out = (float*)d_out;
    char* ws = (char*)d_ws;

    // ---- persistent regions ----
    _Float16* PAD4T = (_Float16*)(ws + 0);           // [130][130][512]
    _Float16* A5T = (_Float16*)(ws + 17305600);      // [4096][512]
    float* STATS = (float*)(ws + 21499904);
    _Float16* H4W = (_Float16*)(ws + 21508096);      // [512][512]
    _Float16* H5W = (_Float16*)(ws + 22032384);
    _Float16* CONVW = (_Float16*)(ws + 22556672);    // [512][4608]
    float* U5 = (float*)(ws + 27275264);
    float* R5 = (float*)(ws + 27283456);
    float* U4 = (float*)(ws + 27291648);
    float* R4 = (float*)(ws + 27299840);
    char* A0 = ws + 27332608;  // arena

    float* cm4 = STATS, *cstd4 = STATS + 512, *cm5 = STATS + 1024,
         *cstd5 = STATS + 1536;

    chanstats_kernel<<<512, 256, 0, stream>>>(content5, cm5, cstd5, 4096);
    chanstats_kernel<<<512, 256, 0, stream>>>(content4, cm4, cstd4, 16384);
    cvt16<<<1024, 256, 0, stream>>>(h4w, H4W);
    cvt16<<<1024, 256, 0, stream>>>(h5w, H5W);
    convw_perm<<<9216, 256, 0, stream>>>(convw, CONVW);

    // ================= Layer 5 (Nc=4096, Ns=1024, Ck=1472) =================
    {
        float* SKT5 = (float*)(A0 + 0);            // [1024][1472]
        float* M5 = (float*)(A0 + 6029312);        // [1536][1536]
        float* T5T = (float*)(A0 + 15466496);      // [1024][1536]
        _Float16* STT5 = (_Float16*)(A0 + 21757952);  // [1024][512]
        _Float16* HCAT5 = (_Float16*)(A0 + 22806528); // [1024][1024]
        float* CKT5 = (float*)(A0 + 24903680);     // [4096][1472]
        float* LOG5 = (float*)(A0 + 49020928);     // [4096][1024] (reused as PV5)
        _Float16* S5 = (_Float16*)(A0 + 65798144); // [4096][1024]
        float* F5WT = CKT5;                        // [1536][1472] scratch
        float* G5WT = (float*)((char*)CKT5 + 9043968);

        transpose_f32<<<dim3(48, 46), 256, 0, stream>>>(f5w, F5WT, 1472, 1472, 1472);
        transpose_f32<<<dim3(48, 46), 256, 0, stream>>>(g5w, G5WT, 1472, 1472, 1472);
        mgemm_split<<<dim3(12, 12), 256, 0, stream>>>(F5WT, G5WT, M5, 1472,
                                                      1472, 1472, 1536);
        transpose_f32<<<dim3(32, 46), 256, 0, stream>>>(skey5, SKT5, 1024, 1472, 1024);
        mgemm_split<<<dim3(12, 8), 256, 0, stream>>>(SKT5, M5, T5T, 1472, 1472,
                                                     1536, 1536);
        transpose_cvt16<<<dim3(32, 16), 256, 0, stream>>>(style5, STT5, 1024, 512);
        mgemm16<2, 2, false><<<dim3(8, 4), 256, 0, stream>>>(
            H5W, STT5, h5b, nullptr, HCAT5, 512, 512, 512, 1024, 0);
        fold_u<<<6, 256, 0, stream>>>(f5b, g5w, U5, 1472, 1472);
        fold_r<<<4, 256, 0, stream>>>(U5, skey5, f5b, g5b, R5, 1472, 1024, 1472);
        transpose_f32<<<dim3(128, 46), 256, 0, stream>>>(ckey5, CKT5, 4096, 1472, 4096);
        mgemm_split<<<dim3(8, 32), 256, 0, stream>>>(CKT5, T5T, LOG5, 1472,
                                                     1472, 1536, 1024);
        softmax_f16<<<4096, 256, 0, stream>>>(LOG5, R5, S5, 1024);
        mgemm16<0, 0, false><<<dim3(8, 32), 256, 0, stream>>>(
            S5, HCAT5, nullptr, LOG5 /*PV*/, nullptr, 1024, 1024, 1024, 1024,
            (size_t)4096 * 1024);
        epilogue5<<<8192, 256, 0, stream>>>(LOG5, content5, cm5, cstd5, A5T);
    }

    // ================= Layer 4 (Nc=16384, Ns=4096, Ck=960) =================
    {
        float* T4T = (float*)(A0 + 0);             // [4096][1024]
        float* M4 = (float*)(A0 + 16777216);       // [1024][1024]
        _Float16* STT4 = (_Float16*)(A0 + 20971520);  // [4096][512]
        _Float16* HCAT4 = (_Float16*)(A0 + 25165824); // [1024][4096]
        float* CKT4 = (float*)(A0 + 33554432);     // [1024][960] per chunk
        _Float16* S4 = (_Float16*)(A0 + 37486592); // [1024][4096]
        float* LOGR = (float*)(A0 + 45875200);     // 16.78MB: SKT4 / LOG4 / PART
        float* F4WT = (float*)(A0 + 20971520);     // scratch pre-STT4
        float* G4WT = (float*)(A0 + 25165824);     // scratch pre-HCAT4

        transpose_f32<<<dim3(32, 30), 256, 0, stream>>>(f4w, F4WT, 960, 960, 960);
        transpose_f32<<<dim3(32, 30), 256, 0, stream>>>(g4w, G4WT, 960, 960, 960);
        mgemm_split<<<dim3(8, 8), 256, 0, stream>>>(F4WT, G4WT, M4, 960, 960,
                                                    960, 1024);
        transpose_f32<<<dim3(128, 30), 256, 0, stream>>>(skey4, LOGR /*SKT4*/,
                                                         4096, 960, 4096);
        mgemm_split<<<dim3(8, 32), 256, 0, stream>>>(LOGR, M4, T4T, 960, 960,
                                                     1024, 1024);
        transpose_cvt16<<<dim3(128, 16), 256, 0, stream>>>(style4, STT4, 4096, 512);
        mgemm16<2, 2, false><<<dim3(32, 4), 256, 0, stream>>>(
            H4W, STT4, h4b, nullptr, HCAT4, 512, 512, 512, 4096, 0);
        fold_u<<<4, 256, 0, stream>>>(f4b, g4w, U4, 960, 960);
        fold_r<<<16, 256, 0, stream>>>(U4, skey4, f4b, g4b, R4, 960, 4096, 960);

        for (int chunk = 0; chunk < 16; chunk++) {
            const int n0 = chunk * 1024;
            transpose_f32<<<dim3(32, 30), 256, 0, stream>>>(ckey4 + n0, CKT4,
                                                            16384, 960, 1024);
            mgemm_split<<<dim3(32, 8), 256, 0, stream>>>(CKT4, T4T, LOGR, 960,
                                                         960, 1024, 4096);
            softmax_f16<<<1024, 256, 0, stream>>>(LOGR, R4, S4, 4096);
            mgemm16<0, 0, false><<<dim3(8, 8, 4), 256, 0, stream>>>(
                S4, HCAT4, nullptr, LOGR /*PART*/, nullptr, 1024, 4096, 4096,
                1024, (size_t)1024 * 1024);
            epilogue4<<<2048, 256, 0, stream>>>(LOGR, content4, cm4, cstd4, A5T,
                                                PAD4T, n0);
        }
    }

    border_kernel<<<1032, 256, 0, stream>>>(PAD4T);
    mgemm16<2, 0, true><<<dim3(128, 4), 256, 0, stream>>>(
        CONVW, PAD4T, convb, out, nullptr, 4608, 4608, 512, 16384, 0);
}

// Round 4
// 2421.623 us; speedup vs baseline: 3.2574x; 1.4833x over previous
//
#include <hip/hip_runtime.h>
#include <math.h>

// ---------------------------------------------------------------------------
// AdaAttN on MI355X. Attention logits via split-fp16 (hi+lo precomputed in
// memory; 3 MFMAs hh+hl+lh) GEMMs with folded weights M = Wf^T Wg. Value and
// conv GEMMs in fp16 MFMA. f32 for logits, softmax, stats, epilogues.
// ---------------------------------------------------------------------------

typedef _Float16 half8 __attribute__((ext_vector_type(8)));
typedef float f32x4 __attribute__((ext_vector_type(4)));

__device__ __forceinline__ void async16(const void* g, void* lds) {
    __builtin_amdgcn_global_load_lds(
        (const __attribute__((address_space(1))) void*)g,
        (__attribute__((address_space(3))) void*)lds, 16, 0, 0);
}

__device__ inline float wave_sum64(float v) {
#pragma unroll
    for (int o = 32; o > 0; o >>= 1) v += __shfl_xor(v, o, 64);
    return v;
}

// ---------------------------------------------------------------------------
// Split-fp16 GEMM v2: C[m][n] = sum_k A[m][k]*B[n][k] where A = Ahi+Alo,
// B = Bhi+Blo (fp16 arrays, k-contig, zero-padded). Drops lo*lo only.
// OUT: 0 = f32 C; 1 = hi/lo fp16 pair outputs (for chained split GEMMs).
// M,N multiples of 128, K multiple of 32.
// ---------------------------------------------------------------------------
template <int OUT>
__global__ __launch_bounds__(256, 2) void mgemm_hl(
    const _Float16* __restrict__ Ahi, const _Float16* __restrict__ Alo,
    const _Float16* __restrict__ Bhi, const _Float16* __restrict__ Blo,
    float* __restrict__ Cf, _Float16* __restrict__ Chi,
    _Float16* __restrict__ Clo, int K, int lda, int ldb, int ldc) {
    __shared__ _Float16 Ash[4096], Asl[4096], Bsh[4096], Bsl[4096];
    const int t = threadIdx.x, wave = t >> 6, lane = t & 63;
    const int bm = blockIdx.y * 128, bn = blockIdx.x * 128;
    const int wr = (wave >> 1) * 64, wc = (wave & 1) * 64;
    const int lq = lane >> 4, lr = lane & 15;
    const int srow = wave * 32 + (lane >> 2);
    const int scolg = (lane & 3) ^ ((lane >> 3) & 3);

    f32x4 acc[4][4] = {};

    const size_t aoff = (size_t)(bm + srow) * lda * 2 + scolg * 16;
    const size_t boff = (size_t)(bn + srow) * ldb * 2 + scolg * 16;
    const char* pAh = (const char*)Ahi + aoff;
    const char* pAl = (const char*)Alo + aoff;
    const char* pBh = (const char*)Bhi + boff;
    const char* pBl = (const char*)Blo + boff;
    const size_t ar = (size_t)16 * lda * 2, br = (size_t)16 * ldb * 2;
    _Float16* dAh = Ash + wave * 1024;
    _Float16* dAl = Asl + wave * 1024;
    _Float16* dBh = Bsh + wave * 1024;
    _Float16* dBl = Bsl + wave * 1024;
    const int key = (lr >> 1) & 3;

    for (int k0 = 0; k0 < K; k0 += 32) {
        __syncthreads();
        async16(pAh, dAh);
        async16(pAh + ar, dAh + 512);
        async16(pAl, dAl);
        async16(pAl + ar, dAl + 512);
        async16(pBh, dBh);
        async16(pBh + br, dBh + 512);
        async16(pBl, dBl);
        async16(pBl + br, dBl + 512);
        pAh += 64;
        pAl += 64;
        pBh += 64;
        pBl += 64;
        __syncthreads();

        half8 ah[4], al[4], bh[4], bl[4];
#pragma unroll
        for (int i = 0; i < 4; i++) {
            const int ro = (wr + i * 16 + lr) * 32 + ((lq ^ key) * 8);
            ah[i] = *(const half8*)&Ash[ro];
            al[i] = *(const half8*)&Asl[ro];
        }
#pragma unroll
        for (int j = 0; j < 4; j++) {
            const int ro = (wc + j * 16 + lr) * 32 + ((lq ^ key) * 8);
            bh[j] = *(const half8*)&Bsh[ro];
            bl[j] = *(const half8*)&Bsl[ro];
        }
#pragma unroll
        for (int i = 0; i < 4; i++)
#pragma unroll
            for (int j = 0; j < 4; j++) {
                acc[i][j] = __builtin_amdgcn_mfma_f32_16x16x32_f16(
                    ah[i], bl[j], acc[i][j], 0, 0, 0);
                acc[i][j] = __builtin_amdgcn_mfma_f32_16x16x32_f16(
                    al[i], bh[j], acc[i][j], 0, 0, 0);
                acc[i][j] = __builtin_amdgcn_mfma_f32_16x16x32_f16(
                    ah[i], bh[j], acc[i][j], 0, 0, 0);
            }
    }
#pragma unroll
    for (int i = 0; i < 4; i++) {
        const int m0 = bm + wr + i * 16 + lq * 4;
#pragma unroll
        for (int j = 0; j < 4; j++) {
            const int n = bn + wc + j * 16 + lr;
#pragma unroll
            for (int r = 0; r < 4; r++) {
                const float v = acc[i][j][r];
                const size_t o = (size_t)(m0 + r) * ldc + n;
                if (OUT == 0) {
                    Cf[o] = v;
                } else {
                    _Float16 h = (_Float16)v;
                    Chi[o] = h;
                    Clo[o] = (_Float16)(v - (float)h);
                }
            }
        }
    }
}

// ---------------------------------------------------------------------------
// fp16 GEMM: C[m][n] = sum_k A[m][k]*B[n][k] (+bias). A,B fp16 k-contig.
// BIAS_MODE: 0 none, 2 bias[m]. OUT_MODE: 0 f32->Cf(+z*splitStride),
// 2 fp16 dual rows (v at m, v*v at m+512). CONV: B = pad4T[py][px][ci].
// ---------------------------------------------------------------------------
template <int BIAS_MODE, int OUT_MODE, bool CONV>
__global__ __launch_bounds__(256, 2) void mgemm16(
    const _Float16* __restrict__ A, const _Float16* __restrict__ B,
    const float* __restrict__ bias, float* __restrict__ Cf,
    _Float16* __restrict__ Ch, int K, int lda, int ldb, int ldc,
    size_t splitStride) {
    __shared__ _Float16 As[128 * 32];
    __shared__ _Float16 Bs[128 * 32];
    const int t = threadIdx.x, wave = t >> 6, lane = t & 63;
    const int bm = blockIdx.y * 128, bn = blockIdx.x * 128;
    const int kbase = blockIdx.z * K;
    const int wr = (wave >> 1) * 64, wc = (wave & 1) * 64;
    const int lq = lane >> 4, lr = lane & 15;
    const int srow = wave * 32 + (lane >> 2);
    const int scolg = (lane & 3) ^ ((lane >> 3) & 3);

    f32x4 acc[4][4] = {};

    const char* Ap = (const char*)A +
                     ((size_t)(bm + srow) * lda + kbase) * 2 + scolg * 16;
    const char* Bp = (const char*)B +
                     ((size_t)(bn + srow) * ldb + kbase) * 2 + scolg * 16;
    const size_t Astep = (size_t)16 * lda * 2;
    const size_t Bstep = (size_t)16 * ldb * 2;
    _Float16* As0 = &As[(wave * 32) * 32];
    _Float16* As1 = &As[(wave * 32 + 16) * 32];
    _Float16* Bs0 = &Bs[(wave * 32) * 32];
    _Float16* Bs1 = &Bs[(wave * 32 + 16) * 32];
    const int key = (lr >> 1) & 3;

    for (int k0 = 0; k0 < K; k0 += 32) {
        __syncthreads();
        async16(Ap, As0);
        async16(Ap + Astep, As1);
        if (CONV) {
            const int kg = kbase + k0;
            const int rI = kg >> 9;
            const int dy = rI / 3, dx = rI - 3 * dy;
            const int ci0 = kg & 511;
            const char* Bc =
                (const char*)B +
                (((size_t)(blockIdx.x + dy) * 130 + srow + dx) * 512 + ci0) * 2 +
                scolg * 16;
            async16(Bc, Bs0);
            async16(Bc + (size_t)16 * 512 * 2, Bs1);
        } else {
            async16(Bp, Bs0);
            async16(Bp + Bstep, Bs1);
            Bp += 64;
        }
        Ap += 64;
        __syncthreads();

        half8 af[4], bf[4];
#pragma unroll
        for (int i = 0; i < 4; i++)
            af[i] = *(const half8*)&As[(wr + i * 16 + lr) * 32 + (lq ^ key) * 8];
#pragma unroll
        for (int j = 0; j < 4; j++)
            bf[j] = *(const half8*)&Bs[(wc + j * 16 + lr) * 32 + (lq ^ key) * 8];
#pragma unroll
        for (int i = 0; i < 4; i++)
#pragma unroll
            for (int j = 0; j < 4; j++)
                acc[i][j] = __builtin_amdgcn_mfma_f32_16x16x32_f16(
                    af[i], bf[j], acc[i][j], 0, 0, 0);
    }

    float* Co = (OUT_MODE == 0) ? Cf + (size_t)blockIdx.z * splitStride : nullptr;
#pragma unroll
    for (int i = 0; i < 4; i++) {
        const int m0 = bm + wr + i * 16 + lq * 4;
#pragma unroll
        for (int j = 0; j < 4; j++) {
            const int n = bn + wc + j * 16 + lr;
#pragma unroll
            for (int r = 0; r < 4; r++) {
                const int m = m0 + r;
                float v = acc[i][j][r];
                if (BIAS_MODE == 2) v += bias[m];
                if (OUT_MODE == 0) {
                    Co[(size_t)m * ldc + n] = v;
                } else {
                    Ch[(size_t)m * ldc + n] = (_Float16)v;
                    Ch[(size_t)(m + 512) * ldc + n] = (_Float16)(v * v);
                }
            }
        }
    }
}

// ---------------------------------------------------------------------------
// transpose f32 -> hi/lo fp16 pair: dsthi/lo[n][c] from src[c][n], zero-fill
// outside (cvalid, nvalid). grid (Npad/32, Cpad/32).
__global__ __launch_bounds__(256) void transpose_hilo(
    const float* __restrict__ src, _Float16* __restrict__ dsthi,
    _Float16* __restrict__ dstlo, long srcld, int dstld, int nvalid,
    int cvalid) {
    __shared__ float tile[32][33];
    const int t = threadIdx.x, tx = t & 31, ty = t >> 5;
    const int n0 = blockIdx.x * 32, c0 = blockIdx.y * 32;
    const int n = n0 + tx;
#pragma unroll
    for (int i = 0; i < 4; i++) {
        int c = c0 + ty + i * 8;
        tile[ty + i * 8][tx] =
            (c < cvalid && n < nvalid) ? src[(size_t)c * srcld + n] : 0.f;
    }
    __syncthreads();
#pragma unroll
    for (int i = 0; i < 4; i++) {
        int nn = ty + i * 8;
        float v = tile[tx][nn];
        _Float16 h = (_Float16)v;
        size_t o = (size_t)(n0 + nn) * dstld + c0 + tx;
        dsthi[o] = h;
        dstlo[o] = (_Float16)(v - (float)h);
    }
}

// transpose f32->fp16 (full-valid). src [C][srcld], dst fp16 [N][dstld].
__global__ __launch_bounds__(256) void transpose_cvt16(
    const float* __restrict__ src, _Float16* __restrict__ dst, long srcld,
    int dstld) {
    __shared__ float tile[32][33];
    const int t = threadIdx.x, tx = t & 31, ty = t >> 5;
    const int n0 = blockIdx.x * 32, c0 = blockIdx.y * 32;
#pragma unroll
    for (int i = 0; i < 4; i++)
        tile[ty + i * 8][tx] = src[(size_t)(c0 + ty + i * 8) * srcld + n0 + tx];
    __syncthreads();
#pragma unroll
    for (int i = 0; i < 4; i++) {
        int nn = ty + i * 8;
        dst[(size_t)(n0 + nn) * dstld + c0 + tx] = (_Float16)tile[tx][nn];
    }
}

// elementwise f32 -> fp16
__global__ __launch_bounds__(256) void cvt16(const float* __restrict__ src,
                                             _Float16* __restrict__ dst) {
    int i = blockIdx.x * 256 + threadIdx.x;
    dst[i] = (_Float16)src[i];
}

// conv weight permute: [o][ci][3][3] f32 -> [o][(dy*3+dx)*512+ci] fp16
__global__ __launch_bounds__(256) void convw_perm(const float* __restrict__ src,
                                                  _Float16* __restrict__ dst) {
    int idx = blockIdx.x * 256 + threadIdx.x;
    int o = idx / 4608, rem = idx - o * 4608;
    int r = rem >> 9, ci = rem & 511;
    dst[idx] = (_Float16)src[(size_t)o * 4608 + ci * 9 + r];
}

// out[n] = (addc ? addc[0] : 0) + sum_c vec[c] * mat[c*ldm + n]
// 64 outputs per block (lane-coalesced); c split over 4 waves, 4 accs each.
__global__ __launch_bounds__(256) void fold_vec(
    const float* __restrict__ mat, const float* __restrict__ vec,
    const float* __restrict__ addc, float* __restrict__ outv, int C, int Nout,
    long ldm) {
    __shared__ float red[4][64];
    const int t = threadIdx.x, lane = t & 63, seg = t >> 6;
    const int n = blockIdx.x * 64 + lane;
    const int chunk = (C + 3) >> 2;
    const int start = seg * chunk;
    const int end = min(C, start + chunk);
    float s0 = 0.f, s1 = 0.f, s2 = 0.f, s3 = 0.f;
    if (n < Nout) {
        int c = start;
        for (; c + 3 < end; c += 4) {
            s0 = fmaf(vec[c], mat[(size_t)c * ldm + n], s0);
            s1 = fmaf(vec[c + 1], mat[(size_t)(c + 1) * ldm + n], s1);
            s2 = fmaf(vec[c + 2], mat[(size_t)(c + 2) * ldm + n], s2);
            s3 = fmaf(vec[c + 3], mat[(size_t)(c + 3) * ldm + n], s3);
        }
        for (; c < end; c++) s0 = fmaf(vec[c], mat[(size_t)c * ldm + n], s0);
    }
    red[seg][lane] = (s0 + s1) + (s2 + s3);
    __syncthreads();
    if (seg == 0 && n < Nout)
        outv[n] = red[0][lane] + red[1][lane] + red[2][lane] + red[3][lane] +
                  (addc ? addc[0] : 0.f);
}

// out[0] = dot(a, b) over C. One block.
__global__ __launch_bounds__(256) void dotbb(const float* __restrict__ a,
                                             const float* __restrict__ b,
                                             float* __restrict__ out, int C) {
    __shared__ float red[4];
    const int t = threadIdx.x;
    float s = 0.f;
    for (int c = t; c < C; c += 256) s = fmaf(a[c], b[c], s);
    s = wave_sum64(s);
    if ((t & 63) == 0) red[t >> 6] = s;
    __syncthreads();
    if (t == 0) out[0] = red[0] + red[1] + red[2] + red[3];
}

// Softmax: f32 logits row (+r[col]) -> fp16 probs row. One block per row.
__global__ __launch_bounds__(256) void softmax_f16(
    const float* __restrict__ L, const float* __restrict__ rr,
    _Float16* __restrict__ S, int cols) {
    __shared__ float red_m[4], red_s[4];
    const int t = threadIdx.x;
    const float* p = L + (size_t)blockIdx.x * cols;
    _Float16* q = S + (size_t)blockIdx.x * cols;
    float mt = -3.0e38f, st = 0.f;
    for (int c = t; c < cols; c += 256) {
        float v = p[c] + rr[c];
        if (v > mt) {
            st = st * __expf(mt - v) + 1.f;
            mt = v;
        } else {
            st += __expf(v - mt);
        }
    }
#pragma unroll
    for (int o = 32; o > 0; o >>= 1) {
        float m2 = __shfl_xor(mt, o, 64), s2 = __shfl_xor(st, o, 64);
        float m = fmaxf(mt, m2);
        st = st * __expf(mt - m) + s2 * __expf(m2 - m);
        mt = m;
    }
    if ((t & 63) == 0) {
        red_m[t >> 6] = mt;
        red_s[t >> 6] = st;
    }
    __syncthreads();
    float M = fmaxf(fmaxf(red_m[0], red_m[1]), fmaxf(red_m[2], red_m[3]));
    float Ssum = red_s[0] * __expf(red_m[0] - M) +
                 red_s[1] * __expf(red_m[1] - M) +
                 red_s[2] * __expf(red_m[2] - M) +
                 red_s[3] * __expf(red_m[3] - M);
    float inv = 1.f / Ssum;
    for (int c = t; c < cols; c += 256)
        q[c] = (_Float16)(__expf(p[c] + rr[c] - M) * inv);
}

// Per-channel mean & unbiased std (+1e-6). One block per channel.
__global__ __launch_bounds__(256) void chanstats_kernel(
    const float* __restrict__ x, float* __restrict__ cm,
    float* __restrict__ cstd, int N) {
    __shared__ float rs[4], rs2[4];
    const int t = threadIdx.x;
    const float* p = x + (size_t)blockIdx.x * N;
    float s = 0.f, s2 = 0.f;
    for (int i = t; i < N; i += 256) {
        float v = p[i];
        s += v;
        s2 = fmaf(v, v, s2);
    }
    s = wave_sum64(s);
    s2 = wave_sum64(s2);
    if ((t & 63) == 0) {
        rs[t >> 6] = s;
        rs2[t >> 6] = s2;
    }
    __syncthreads();
    if (t == 0) {
        float S = rs[0] + rs[1] + rs[2] + rs[3];
        float S2 = rs2[0] + rs2[1] + rs2[2] + rs2[3];
        float mean = S / N;
        float var = fmaxf((S2 - S * mean) / (N - 1), 0.f);
        cm[blockIdx.x] = mean;
        cstd[blockIdx.x] = sqrtf(var) + 1e-6f;
    }
}

// a5T[n][c] fp16 = std*instnorm(content5) + mean
__global__ __launch_bounds__(256) void epilogue5(
    const float* __restrict__ pv, const float* __restrict__ content,
    const float* __restrict__ cm, const float* __restrict__ cstd,
    _Float16* __restrict__ a5t) {
    int idx = blockIdx.x * 256 + threadIdx.x;  // n*512 + c
    int n = idx >> 9, c = idx & 511;
    float mean = pv[(size_t)n * 1024 + c];
    float ex2 = pv[(size_t)n * 1024 + 512 + c];
    float sd = sqrtf(fmaxf(ex2 - mean * mean, 0.f));
    float cn = (content[(size_t)c * 4096 + n] - cm[c]) / cstd[c];
    a5t[idx] = (_Float16)(fmaf(sd, cn, mean));
}

// pad4T interior <- a4 + upsample2(a5), one 1024-pixel chunk, 4 K-splits.
__global__ __launch_bounds__(256) void epilogue4(
    const float* __restrict__ part, const float* __restrict__ content,
    const float* __restrict__ cm, const float* __restrict__ cstd,
    const _Float16* __restrict__ a5t, _Float16* __restrict__ pad4t, int n0) {
    int idx = blockIdx.x * 256 + threadIdx.x;  // r*512 + c
    int r = idx >> 9, c = idx & 511;
    int n = n0 + r;
    const size_t SS = (size_t)1024 * 1024;
    float mean = 0.f, ex2 = 0.f;
#pragma unroll
    for (int z = 0; z < 4; z++) {
        mean += part[z * SS + (size_t)r * 1024 + c];
        ex2 += part[z * SS + (size_t)r * 1024 + 512 + c];
    }
    float sd = sqrtf(fmaxf(ex2 - mean * mean, 0.f));
    float cn = (content[(size_t)c * 16384 + n] - cm[c]) / cstd[c];
    int y = n >> 7, x = n & 127;
    float up = (float)a5t[(size_t)((y >> 1) * 64 + (x >> 1)) * 512 + c];
    pad4t[(size_t)((y + 1) * 130 + (x + 1)) * 512 + c] =
        (_Float16)(fmaf(sd, cn, mean) + up);
}

__global__ __launch_bounds__(256) void border_kernel(_Float16* __restrict__ pad) {
    int idx = blockIdx.x * 256 + threadIdx.x;  // pos*512 + c
    int pos = idx >> 9, c = idx & 511;
    int py, px;
    if (pos < 130) { py = 0; px = pos; }
    else if (pos < 260) { py = 129; px = pos - 130; }
    else if (pos < 388) { py = pos - 260 + 1; px = 0; }
    else { py = pos - 388 + 1; px = 129; }
    int sy = py == 0 ? 2 : (py == 129 ? 127 : py);
    int sx = px == 0 ? 2 : (px == 129 ? 127 : px);
    pad[(size_t)(py * 130 + px) * 512 + c] =
        pad[(size_t)(sy * 130 + sx) * 512 + c];
}

// ---------------------------------------------------------------------------

extern "C" void kernel_launch(void* const* d_in, const int* in_sizes, int n_in,
                              void* d_out, int out_size, void* d_ws,
                              size_t ws_size, hipStream_t stream) {
    (void)in_sizes; (void)n_in; (void)out_size; (void)ws_size;
    const float* content4 = (const float*)d_in[0];
    const float* style4 = (const float*)d_in[1];
    const float* content5 = (const float*)d_in[2];
    const float* style5 = (const float*)d_in[3];
    const float* ckey4 = (const float*)d_in[4];
    const float* skey4 = (const float*)d_in[5];
    const float* ckey5 = (const float*)d_in[6];
    const float* skey5 = (const float*)d_in[7];
    const float* f4w = (const float*)d_in[8];
    const float* f4b = (const float*)d_in[9];
    const float* g4w = (const float*)d_in[10];
    const float* g4b = (const float*)d_in[11];
    const float* h4w = (const float*)d_in[12];
    const float* h4b = (const float*)d_in[13];
    const float* f5w = (const float*)d_in[14];
    const float* f5b = (const float*)d_in[15];
    const float* g5w = (const float*)d_in[16];
    const float* g5b = (const float*)d_in[17];
    const float* h5w = (const float*)d_in[18];
    const float* h5b = (const float*)d_in[19];
    const float* convw = (const float*)d_in[20];
    const float* convb = (const float*)d_in[21];
    float* out = (float*)d_out;
    char* ws = (char*)d_ws;

    // ---- persistent regions (byte offsets) ----
    _Float16* PAD4T = (_Float16*)(ws + 0);         // [130][130][512]
    _Float16* A5T = (_Float16*)(ws + 17305600);    // [4096][512]
    float* STATS = (float*)(ws + 21499904);        // 2048 f32
    _Float16* H4W = (_Float16*)(ws + 21508096);    // [512][512]
    _Float16* H5W = (_Float16*)(ws + 22032384);
    _Float16* CONVW = (_Float16*)(ws + 22556672);  // [512][4608]
    float* U5 = (float*)(ws + 27275264);           // 1472
    float* R5 = (float*)(ws + 27283456);           // 1024
    float* U4 = (float*)(ws + 27291648);           // 960
    float* R4 = (float*)(ws + 27299840);           // 4096
    float* BB5 = (float*)(ws + 27316224);
    float* BB4 = (float*)(ws + 27316480);
    char* A0 = ws + 27320320;  // arena

    float* cm4 = STATS, *cstd4 = STATS + 512, *cm5 = STATS + 1024,
         *cstd5 = STATS + 1536;

    chanstats_kernel<<<512, 256, 0, stream>>>(content5, cm5, cstd5, 4096);
    chanstats_kernel<<<512, 256, 0, stream>>>(content4, cm4, cstd4, 16384);
    cvt16<<<1024, 256, 0, stream>>>(h4w, H4W);
    cvt16<<<1024, 256, 0, stream>>>(h5w, H5W);
    convw_perm<<<9216, 256, 0, stream>>>(convw, CONVW);

    // ================= Layer 5 (Nc=4096, Ns=1024, Ck=1472->1536) ===========
    {
        _Float16* M5h = (_Float16*)(A0 + 0);          // [1536][1536]
        _Float16* M5l = (_Float16*)(A0 + 4718592);
        _Float16* FWh = (_Float16*)(A0 + 9437184);    // [1536][1536]
        _Float16* FWl = (_Float16*)(A0 + 14155776);
        _Float16* GWh = (_Float16*)(A0 + 18874368);
        _Float16* GWl = (_Float16*)(A0 + 23592960);
        _Float16* SKh = (_Float16*)(A0 + 9437184);    // [1024][1536] (post-M)
        _Float16* SKl = (_Float16*)(A0 + 12582912);
        _Float16* T5h = (_Float16*)(A0 + 15728640);   // [1024][1536]
        _Float16* T5l = (_Float16*)(A0 + 18874368);
        _Float16* STT5 = (_Float16*)(A0 + 0);         // [1024][512] (post-T)
        _Float16* HCAT5 = (_Float16*)(A0 + 1048576);  // [1024][1024]
        _Float16* CKh = (_Float16*)(A0 + 22020096);   // [4096][1536]
        _Float16* CKl = (_Float16*)(A0 + 34603008);
        float* LOG5 = (float*)(A0 + 47185920);        // [4096][1024] f32
        _Float16* S5 = (_Float16*)(A0 + 63963136);    // [4096][1024]

        // folds (cheap, independent)
        dotbb<<<1, 256, 0, stream>>>(f5b, g5b, BB5, 1472);
        fold_vec<<<23, 256, 0, stream>>>(g5w, f5b, nullptr, U5, 1472, 1472, 1472);
        fold_vec<<<16, 256, 0, stream>>>(skey5, U5, BB5, R5, 1472, 1024, 1024);

        transpose_hilo<<<dim3(48, 48), 256, 0, stream>>>(f5w, FWh, FWl, 1472,
                                                         1536, 1472, 1472);
        transpose_hilo<<<dim3(48, 48), 256, 0, stream>>>(g5w, GWh, GWl, 1472,
                                                         1536, 1472, 1472);
        mgemm_hl<1><<<dim3(12, 12), 256, 0, stream>>>(
            FWh, FWl, GWh, GWl, nullptr, M5h, M5l, 1536, 1536, 1536, 1536);
        transpose_hilo<<<dim3(32, 48), 256, 0, stream>>>(skey5, SKh, SKl, 1024,
                                                         1536, 1024, 1472);
        mgemm_hl<1><<<dim3(12, 8), 256, 0, stream>>>(
            SKh, SKl, M5h, M5l, nullptr, T5h, T5l, 1536, 1536, 1536, 1536);
        transpose_cvt16<<<dim3(32, 16), 256, 0, stream>>>(style5, STT5, 1024, 512);
        mgemm16<2, 2, false><<<dim3(8, 4), 256, 0, stream>>>(
            H5W, STT5, h5b, nullptr, HCAT5, 512, 512, 512, 1024, 0);
        transpose_hilo<<<dim3(128, 48), 256, 0, stream>>>(ckey5, CKh, CKl, 4096,
                                                          1536, 4096, 1472);
        mgemm_hl<0><<<dim3(8, 32), 256, 0, stream>>>(
            CKh, CKl, T5h, T5l, LOG5, nullptr, nullptr, 1536, 1536, 1536, 1024);
        softmax_f16<<<4096, 256, 0, stream>>>(LOG5, R5, S5, 1024);
        mgemm16<0, 0, false><<<dim3(8, 32), 256, 0, stream>>>(
            S5, HCAT5, nullptr, LOG5 /*PV*/, nullptr, 1024, 1024, 1024, 1024,
            (size_t)4096 * 1024);
        epilogue5<<<8192, 256, 0, stream>>>(LOG5, content5, cm5, cstd5, A5T);
    }

    // ================= Layer 4 (Nc=16384, Ns=4096, Ck=960->1024) ===========
    {
        _Float16* T4h = (_Float16*)(A0 + 0);          // [4096][1024]
        _Float16* T4l = (_Float16*)(A0 + 8388608);
        _Float16* M4h = (_Float16*)(A0 + 16777216);   // [1024][1024]
        _Float16* M4l = (_Float16*)(A0 + 18874368);
        _Float16* FWh = (_Float16*)(A0 + 20971520);   // [1024][1024]
        _Float16* FWl = (_Float16*)(A0 + 23068672);
        _Float16* GWh = (_Float16*)(A0 + 25165824);
        _Float16* GWl = (_Float16*)(A0 + 27262976);
        _Float16* SKh = (_Float16*)(A0 + 29360128);   // [4096][1024]
        _Float16* SKl = (_Float16*)(A0 + 37748736);
        _Float16* STT4 = (_Float16*)(A0 + 16777216);  // [4096][512] (post-T)
        _Float16* HCAT4 = (_Float16*)(A0 + 20971520); // [1024][4096]
        _Float16* CKh = (_Float16*)(A0 + 29360128);   // [1024][1024] per chunk
        _Float16* CKl = (_Float16*)(A0 + 31457280);
        _Float16* S4 = (_Float16*)(A0 + 33554432);    // [1024][4096]
        float* LOGR = (float*)(A0 + 41943040);        // [1024][4096] f32 / PART

        dotbb<<<1, 256, 0, stream>>>(f4b, g4b, BB4, 960);
        fold_vec<<<15, 256, 0, stream>>>(g4w, f4b, nullptr, U4, 960, 960, 960);
        fold_vec<<<64, 256, 0, stream>>>(skey4, U4, BB4, R4, 960, 4096, 4096);

        transpose_hilo<<<dim3(32, 32), 256, 0, stream>>>(f4w, FWh, FWl, 960,
                                                         1024, 960, 960);
        transpose_hilo<<<dim3(32, 32), 256, 0, stream>>>(g4w, GWh, GWl, 960,
                                                         1024, 960, 960);
        mgemm_hl<1><<<dim3(8, 8), 256, 0, stream>>>(
            FWh, FWl, GWh, GWl, nullptr, M4h, M4l, 1024, 1024, 1024, 1024);
        transpose_hilo<<<dim3(128, 32), 256, 0, stream>>>(skey4, SKh, SKl, 4096,
                                                          1024, 4096, 960);
        mgemm_hl<1><<<dim3(8, 32), 256, 0, stream>>>(
            SKh, SKl, M4h, M4l, nullptr, T4h, T4l, 1024, 1024, 1024, 1024);
        transpose_cvt16<<<dim3(128, 16), 256, 0, stream>>>(style4, STT4, 4096, 512);
        mgemm16<2, 2, false><<<dim3(32, 4), 256, 0, stream>>>(
            H4W, STT4, h4b, nullptr, HCAT4, 512, 512, 512, 4096, 0);

        for (int chunk = 0; chunk < 16; chunk++) {
            const int n0 = chunk * 1024;
            transpose_hilo<<<dim3(32, 32), 256, 0, stream>>>(
                ckey4 + n0, CKh, CKl, 16384, 1024, 1024, 960);
            mgemm_hl<0><<<dim3(32, 8), 256, 0, stream>>>(
                CKh, CKl, T4h, T4l, LOGR, nullptr, nullptr, 1024, 1024, 1024,
                4096);
            softmax_f16<<<1024, 256, 0, stream>>>(LOGR, R4, S4, 4096);
            mgemm16<0, 0, false><<<dim3(8, 8, 4), 256, 0, stream>>>(
                S4, HCAT4, nullptr, LOGR /*PART*/, nullptr, 1024, 4096, 4096,
                1024, (size_t)1024 * 1024);
            epilogue4<<<2048, 256, 0, stream>>>(LOGR, content4, cm4, cstd4, A5T,
                                                PAD4T, n0);
        }
    }

    border_kernel<<<1032, 256, 0, stream>>>(PAD4T);
    mgemm16<2, 0, true><<<dim3(128, 4), 256, 0, stream>>>(
        CONVW, PAD4T, convb, out, nullptr, 4608, 4608, 512, 16384, 0);
}